// Round 2
// baseline (195.281 us; speedup 1.0000x reference)
//
#include <hip/hip_runtime.h>
#include <stdint.h>

// RGCNConv: out = sum_r ((A * [edge==r]) @ x) @ W_r + bias
// N=4096, IN=OUT=256, R=8.
//   k_init : out[i][o] = bias[o]
//   k_y    : y_t[o][j*8+r] = (x @ W_r)[j][o]  (bf16, in ws, 16 MB)
//   k_main : expanded GEMM out[i][o] += sum_j A[i][j] * y_t[o][j*8+e[i][j]]
//            A one-hot frags built in registers; B via global_load_lds dbuf.

#define NN 4096

typedef __attribute__((ext_vector_type(8))) short  s16x8;   // 8 bf16 MFMA frag
typedef __attribute__((ext_vector_type(4))) float  fx4;
typedef __attribute__((ext_vector_type(4))) int    ix4;
typedef __attribute__((ext_vector_type(4))) unsigned int ux4;

union uq { ux4 u; s16x8 s; };

__device__ __forceinline__ unsigned short f2bf(float f) {
  union { float f; unsigned int u; } v; v.f = f;
  unsigned int r = v.u + 0x7fffu + ((v.u >> 16) & 1u);  // RNE
  return (unsigned short)(r >> 16);
}

// direct global->LDS DMA, 16B per lane. LDS dest must be wave-uniform base
// (HW adds lane*16). Addrspace casts via uintptr (CK pattern; apertures are
// 4GB-aligned so truncation to AS3 offset is valid).
__device__ __forceinline__ void gld16(const void* g, void* l) {
  __builtin_amdgcn_global_load_lds(
      (const __attribute__((address_space(1))) unsigned int*)(uintptr_t)g,
      (__attribute__((address_space(3))) unsigned int*)(uintptr_t)l, 16, 0, 0);
}

// ---------------- init: out = bias ----------------
__global__ void k_init(const float* __restrict__ bias, float* __restrict__ out) {
  int idx = blockIdx.x * 256 + threadIdx.x;
  out[idx] = bias[idx & 255];
}

// ---------------- y_t[o][j*8+r] = sum_k x[j][k] * W[r][k][o] ----------------
__global__ __launch_bounds__(256) void k_y(const float* __restrict__ x,
                                           const float* __restrict__ W,
                                           unsigned short* __restrict__ yt) {
  __shared__ unsigned short Wl[128 * 256];  // 64 KB
  const int t  = threadIdx.x;
  const int j0 = blockIdx.x * 64;
  const int o0 = blockIdx.y * 16;

  {
    const int r = t >> 5, kc = t & 31;
#pragma unroll
    for (int u = 0; u < 8; ++u) {
      const int k = kc * 8 + u;
      const fx4* wp = (const fx4*)(W + ((size_t)r * 256 + k) * 256 + o0);
      fx4 w[4] = { wp[0], wp[1], wp[2], wp[3] };
#pragma unroll
      for (int i = 0; i < 16; ++i) {
        const int row = i * 8 + r;               // n'
        const int gs  = (k >> 3) ^ (row & 7);    // swizzled 16B granule
        Wl[row * 256 + gs * 8 + (k & 7)] = f2bf(w[i >> 2][i & 3]);
      }
    }
  }
  __syncthreads();

  const int lane = t & 63, wid = t >> 6;
  const int l15 = lane & 15, lh = lane >> 4;
  const int npb = wid * 32;

  fx4 acc[4][2];
#pragma unroll
  for (int m = 0; m < 4; ++m)
#pragma unroll
    for (int n = 0; n < 2; ++n) acc[m][n] = 0.f;

  unsigned int qb[2];
#pragma unroll
  for (int n = 0; n < 2; ++n) {
    int row = npb + n * 16 + l15;
    qb[n] = (unsigned)(row * 512 + 16 * (lh ^ (row & 3))) ^ (64u * ((row >> 2) & 1));
  }
  const char* WlB = (const char*)Wl;
  const float* xb = x + (size_t)(j0 + l15) * 256 + lh * 8;

#pragma unroll
  for (int ks = 0; ks < 8; ++ks) {
    s16x8 a[4];
#pragma unroll
    for (int m = 0; m < 4; ++m) {
      const fx4* xp = (const fx4*)(xb + (size_t)m * 16 * 256 + ks * 32);
      fx4 x0 = xp[0], x1 = xp[1];
      s16x8 av;
#pragma unroll
      for (int i = 0; i < 4; ++i) av[i] = (short)f2bf(x0[i]);
#pragma unroll
      for (int i = 0; i < 4; ++i) av[4 + i] = (short)f2bf(x1[i]);
      a[m] = av;
    }
#pragma unroll
    for (int n = 0; n < 2; ++n) {
      s16x8 b = *(const s16x8*)(WlB + (qb[n] ^ (unsigned)(ks * 64)));
#pragma unroll
      for (int m = 0; m < 4; ++m)
        acc[m][n] = __builtin_amdgcn_mfma_f32_16x16x32_bf16(a[m], b, acc[m][n], 0, 0, 0);
    }
  }

#pragma unroll
  for (int m = 0; m < 4; ++m)
#pragma unroll
    for (int n = 0; n < 2; ++n)
#pragma unroll
      for (int q = 0; q < 4; ++q) {
        int jl = m * 16 + lh * 4 + q;
        int np = npb + n * 16 + l15;
        int o  = o0 + (np >> 3);
        yt[(size_t)o * 32768 + (size_t)(j0 + jl) * 8 + (np & 7)] = f2bf(acc[m][n][q]);
      }
}

// ---------------- main expanded GEMM ----------------
// grid (16 mtiles, 2 ntiles, 16 ksplit), 256 thr (4 waves).
// Block tile 256x128; wave tile 64x128 (m-split). 16 steps x 16 j (K_eff 128).
// B (yt granules) double-buffered in LDS via global_load_lds, swizzled source:
//   LDS slot sl of row holds global granule (j0 + (sl ^ (row&15))).
// Frag read (k-slice ks, lane lh) uses logical granule g = lh*4+ks:
//   byte = row*256 + 16*(g ^ (row&15))  -> conflict-free ds_read_b128.
// A one-hot fragment built in registers: granule (i,j) = hv at slot e[i][j].
__global__ __launch_bounds__(256, 2) void k_main(const float* __restrict__ A,
                                                 const int*   __restrict__ et,
                                                 const unsigned short* __restrict__ yt,
                                                 float* __restrict__ out) {
  __shared__ ux4 Bl[2 * 2048];  // 2 x 128 rows x 16 granules = 64 KB
  const int t = threadIdx.x, lane = t & 63, wid = t >> 6;
  const int l15 = lane & 15, lh = lane >> 4;
  const int i0 = blockIdx.x * 256;
  const int o0 = blockIdx.y * 128;
  const int jb = blockIdx.z * 256;   // j-window of 256 (16 steps x 16)

  const ux4* ytg = (const ux4*)yt;   // granule view: [o][4096]

  // A/et lane bases: rows i = i0 + wid*64 + m*16 + l15, col jb + lh*4
  const float* pA[4]; const int* pE[4];
#pragma unroll
  for (int m = 0; m < 4; ++m) {
    size_t off = (size_t)(i0 + wid * 64 + m * 16 + l15) * NN + jb + lh * 4;
    pA[m] = A + off; pE[m] = et + off;
  }

  // prologue: A/et step 0 + stage B step 0 into buf 0
  fx4 raC[4]; ix4 reC[4];
#pragma unroll
  for (int m = 0; m < 4; ++m) { raC[m] = *(const fx4*)pA[m]; reC[m] = *(const ix4*)pE[m]; }
#pragma unroll
  for (int u = 0; u < 8; ++u) {
    int row = wid * 32 + u * 4 + lh;
    int gj  = l15 ^ ((u * 4 + lh) & 15);
    gld16(ytg + ((size_t)(o0 + row) << 12) + jb + gj, Bl + wid * 512 + u * 64);
  }
  __syncthreads();

  fx4 acc[4][8];
#pragma unroll
  for (int m = 0; m < 4; ++m)
#pragma unroll
    for (int n = 0; n < 8; ++n) acc[m][n] = 0.f;

  const char* ldsc = (const char*)Bl;

  for (int s = 0; s < 16; ++s) {
    const int sn = (s < 15) ? s + 1 : s;   // clamped next step
    const int nb = (s + 1) & 1;
    // stage next B tile (DMA, stays in flight until end-of-step barrier drain)
#pragma unroll
    for (int u = 0; u < 8; ++u) {
      int row = wid * 32 + u * 4 + lh;
      int gj  = l15 ^ ((u * 4 + lh) & 15);
      gld16(ytg + ((size_t)(o0 + row) << 12) + jb + sn * 16 + gj,
            Bl + nb * 2048 + wid * 512 + u * 64);
    }
    // prefetch next A/et (one dwordx4 each per m: j = jb + s'*16 + lh*4 + 0..3)
    fx4 raN[4]; ix4 reN[4];
#pragma unroll
    for (int m = 0; m < 4; ++m) {
      raN[m] = *(const fx4*)(pA[m] + sn * 16);
      reN[m] = *(const ix4*)(pE[m] + sn * 16);
    }
    // compute current step from buf s&1
    const unsigned bufoff = (unsigned)(s & 1) * 32768u;
#pragma unroll
    for (int ks = 0; ks < 4; ++ks) {
      uq a4[4];
#pragma unroll
      for (int m = 0; m < 4; ++m) {
        float av; int ev;
        if      (ks == 0) { av = raC[m].x; ev = reC[m].x; }
        else if (ks == 1) { av = raC[m].y; ev = reC[m].y; }
        else if (ks == 2) { av = raC[m].z; ev = reC[m].z; }
        else              { av = raC[m].w; ev = reC[m].w; }
        unsigned long long sh = ((unsigned long long)f2bf(av)) << ((ev & 3) * 16);
        unsigned lo = (unsigned)sh, hi = (unsigned)(sh >> 32);
        bool c = ev < 4;
        ux4 q;
        q.x = c ? lo : 0u; q.y = c ? hi : 0u; q.z = c ? 0u : lo; q.w = c ? 0u : hi;
        a4[m].u = q;
      }
#pragma unroll
      for (int n = 0; n < 8; ++n) {
        int row = n * 16 + l15;
        unsigned off = bufoff + (unsigned)(row << 8)
                     + (unsigned)((((lh * 4 + ks) ^ (row & 15)) << 4));
        uq b; b.u = *(const ux4*)(ldsc + off);
#pragma unroll
        for (int m = 0; m < 4; ++m)
          acc[m][n] = __builtin_amdgcn_mfma_f32_16x16x32_bf16(a4[m].s, b.s, acc[m][n], 0, 0, 0);
      }
    }
#pragma unroll
    for (int m = 0; m < 4; ++m) { raC[m] = raN[m]; reC[m] = reN[m]; }
    __syncthreads();  // drains: stage(s+1) + raN loads done; buf reads done
  }

  // epilogue: K-split partial accumulate
#pragma unroll
  for (int m = 0; m < 4; ++m)
#pragma unroll
    for (int n = 0; n < 8; ++n)
#pragma unroll
      for (int q = 0; q < 4; ++q) {
        int gi = i0 + wid * 64 + m * 16 + lh * 4 + q;
        int go = o0 + n * 16 + l15;
        atomicAdd(out + (size_t)gi * 256 + go, acc[m][n][q]);
      }
}

extern "C" void kernel_launch(void* const* d_in, const int* in_sizes, int n_in,
                              void* d_out, int out_size, void* d_ws, size_t ws_size,
                              hipStream_t stream) {
  const float* x    = (const float*)d_in[0];
  const float* A    = (const float*)d_in[1];
  const int*   et   = (const int*)d_in[2];
  const float* W    = (const float*)d_in[3];
  const float* bias = (const float*)d_in[4];
  float* out = (float*)d_out;
  unsigned short* yt = (unsigned short*)d_ws;  // 256*32768*2 = 16 MB

  k_init<<<dim3(4096), dim3(256), 0, stream>>>(bias, out);
  k_y   <<<dim3(64, 16), dim3(256), 0, stream>>>(x, W, yt);
  k_main<<<dim3(16, 2, 16), dim3(256), 0, stream>>>(A, et, yt, out);
}